// Round 1
// baseline (666.045 us; speedup 1.0000x reference)
//
#include <hip/hip_runtime.h>
#include <hip/hip_bf16.h>

#define TOK 16384   // B*S
#define E 2048
#define NH 16
#define DH 128

using bf16x8 = __attribute__((ext_vector_type(8))) __bf16;
using f32x4  = __attribute__((ext_vector_type(4))) float;
using u16x8  = __attribute__((ext_vector_type(8))) unsigned short;

static __device__ __forceinline__ unsigned short f2bf(float f) {
  union { float f; unsigned u; } x; x.f = f;
  unsigned r = x.u + 0x7fffu + ((x.u >> 16) & 1u);   // RNE
  return (unsigned short)(r >> 16);
}

static __device__ __forceinline__ void gload_lds16(const unsigned short* g, unsigned short* l) {
  __builtin_amdgcn_global_load_lds(
      (const __attribute__((address_space(1))) void*)g,
      (__attribute__((address_space(3))) void*)l, 16, 0, 0);
}

// ---------------- prep kernels (fp32 -> bf16, with optional row scaling) ----------------
__global__ __launch_bounds__(256) void cvt_plain(const float* __restrict__ in,
                                                 unsigned short* __restrict__ out, int n8) {
  int stride = gridDim.x * blockDim.x;
  for (int i = blockIdx.x * blockDim.x + threadIdx.x; i < n8; i += stride) {
    const float4* p = reinterpret_cast<const float4*>(in) + (size_t)i * 2;
    float4 v0 = p[0], v1 = p[1];
    u16x8 o;
    o[0] = f2bf(v0.x); o[1] = f2bf(v0.y); o[2] = f2bf(v0.z); o[3] = f2bf(v0.w);
    o[4] = f2bf(v1.x); o[5] = f2bf(v1.y); o[6] = f2bf(v1.z); o[7] = f2bf(v1.w);
    *(reinterpret_cast<u16x8*>(out) + i) = o;
  }
}

// Wz row n scaled by sin(phase[n]) / sqrt(Dh)  (phase flattened [H*Dh] == [E])
__global__ __launch_bounds__(256) void cvt_scaled(const float* __restrict__ in,
                                                  const float* __restrict__ phase,
                                                  unsigned short* __restrict__ out, int n8) {
  const float rs = 0.08838834764831845f;  // 1/sqrt(128)
  int stride = gridDim.x * blockDim.x;
  for (int i = blockIdx.x * blockDim.x + threadIdx.x; i < n8; i += stride) {
    int row = i >> 8;  // (i*8) / 2048
    float sc = sinf(phase[row]) * rs;
    const float4* p = reinterpret_cast<const float4*>(in) + (size_t)i * 2;
    float4 v0 = p[0], v1 = p[1];
    u16x8 o;
    o[0] = f2bf(v0.x * sc); o[1] = f2bf(v0.y * sc); o[2] = f2bf(v0.z * sc); o[3] = f2bf(v0.w * sc);
    o[4] = f2bf(v1.x * sc); o[5] = f2bf(v1.y * sc); o[6] = f2bf(v1.z * sc); o[7] = f2bf(v1.w * sc);
    *(reinterpret_cast<u16x8*>(out) + i) = o;
  }
}

__global__ __launch_bounds__(256) void scale_bias(const float* __restrict__ bz,
                                                  const float* __restrict__ phase,
                                                  float* __restrict__ out) {
  const float rs = 0.08838834764831845f;
  int i = blockIdx.x * blockDim.x + threadIdx.x;
  if (i < E) out[i] = bz[i] * sinf(phase[i]) * rs;
}

// ---------------- GEMM: C[M,N] = A[M,K] @ B[N,K]^T + bias, bf16 in, fp32 acc ----------------
// m97 structure: 128x128 tile, BK=32, 256 threads = 4 waves (2x2 of 64x64),
// global_load_lds width 16 staging, 16x16x32 bf16 MFMA, 4x4 fragments/wave.
template <bool OUT_BF16>
__global__ __launch_bounds__(256) void gemm_bt(const unsigned short* __restrict__ A,
                                               const unsigned short* __restrict__ Bm,
                                               const float* __restrict__ bias,
                                               void* __restrict__ C,
                                               int M, int N, int K) {
  __shared__ __align__(16) unsigned short sA[128 * 32];
  __shared__ __align__(16) unsigned short sB[128 * 32];

  const int nbn = N >> 7;
  const int bx = blockIdx.x % nbn;
  const int by = blockIdx.x / nbn;
  const int tm = by << 7, tn = bx << 7;

  const int tid  = threadIdx.x;
  const int wave = tid >> 6, lane = tid & 63;
  const int wr = wave >> 1, wc = wave & 1;
  const int g16 = lane & 15, grp = lane >> 4;
  const int lrow = lane >> 2, lcol = (lane & 3) * 8;  // staging: 16 rows x 32 cols per wave-call

  f32x4 acc[4][4];
#pragma unroll
  for (int i = 0; i < 4; ++i)
#pragma unroll
    for (int j = 0; j < 4; ++j) acc[i][j] = (f32x4){0.f, 0.f, 0.f, 0.f};

  for (int k0 = 0; k0 < K; k0 += 32) {
#pragma unroll
    for (int i = 0; i < 2; ++i) {
      const int chunk = wave * 2 + i;          // 0..7 -> rows chunk*16..+16
      const int row = chunk * 16 + lrow;
      gload_lds16(A + (size_t)(tm + row) * K + k0 + lcol, sA + chunk * 512);
      gload_lds16(Bm + (size_t)(tn + row) * K + k0 + lcol, sB + chunk * 512);
    }
    __syncthreads();

    bf16x8 af[4], bfr[4];
#pragma unroll
    for (int mi = 0; mi < 4; ++mi)
      af[mi] = *reinterpret_cast<const bf16x8*>(sA + (wr * 64 + mi * 16 + g16) * 32 + grp * 8);
#pragma unroll
    for (int ni = 0; ni < 4; ++ni)
      bfr[ni] = *reinterpret_cast<const bf16x8*>(sB + (wc * 64 + ni * 16 + g16) * 32 + grp * 8);

#pragma unroll
    for (int mi = 0; mi < 4; ++mi)
#pragma unroll
      for (int ni = 0; ni < 4; ++ni)
        acc[mi][ni] = __builtin_amdgcn_mfma_f32_16x16x32_bf16(af[mi], bfr[ni], acc[mi][ni], 0, 0, 0);

    __syncthreads();
  }

  // epilogue: C row = (lane>>4)*4 + j, col = lane&15 within each 16x16 fragment
#pragma unroll
  for (int mi = 0; mi < 4; ++mi) {
#pragma unroll
    for (int ni = 0; ni < 4; ++ni) {
      const int row = tm + wr * 64 + mi * 16 + grp * 4;
      const int col = tn + wc * 64 + ni * 16 + g16;
      const float bv = bias[col];
#pragma unroll
      for (int j = 0; j < 4; ++j) {
        const float v = acc[mi][ni][j] + bv;
        if (OUT_BF16)
          ((unsigned short*)C)[(size_t)(row + j) * N + col] = f2bf(v);
        else
          ((float*)C)[(size_t)(row + j) * N + col] = v;
      }
    }
  }
}

// ---------------- per-token head-mixing attention ----------------
// 4 waves/block, 1 token/wave. scores = mod(16x128) @ xs(16x128)^T via 4 MFMAs
// (fragments loaded straight from global); softmax over g via shfl within
// 16-lane groups; PV via VALU from LDS-staged xs. att may alias mod (in-place).
__global__ __launch_bounds__(256) void attn_kernel(const unsigned short* mod,
                                                   const unsigned short* xsg,
                                                   unsigned short* att) {
  __shared__ __align__(16) unsigned short xs_lds[4][16][136];  // +8 pad
  __shared__ float w_lds[4][16][17];

  const int wave = threadIdx.x >> 6, lane = threadIdx.x & 63;
  const int token = (blockIdx.x << 2) | wave;
  const unsigned short* modp = mod + (size_t)token * E;
  const unsigned short* xsp  = xsg + (size_t)token * E;
  const int g16 = lane & 15, grp = lane >> 4;

  bf16x8 a[4], b[4];
#pragma unroll
  for (int kk = 0; kk < 4; ++kk) {
    a[kk] = *reinterpret_cast<const bf16x8*>(modp + g16 * DH + kk * 32 + grp * 8);
    b[kk] = *reinterpret_cast<const bf16x8*>(xsp  + g16 * DH + kk * 32 + grp * 8);
  }
#pragma unroll
  for (int kk = 0; kk < 4; ++kk)
    *reinterpret_cast<bf16x8*>(&xs_lds[wave][g16][kk * 32 + grp * 8]) = b[kk];

  f32x4 sc = (f32x4){0.f, 0.f, 0.f, 0.f};
#pragma unroll
  for (int kk = 0; kk < 4; ++kk)
    sc = __builtin_amdgcn_mfma_f32_16x16x32_bf16(a[kk], b[kk], sc, 0, 0, 0);
  // lane holds scores[h = grp*4+j][g = g16]  (scale already folded into Wz)

  float w4[4];
#pragma unroll
  for (int j = 0; j < 4; ++j) {
    float s = sc[j];
    float m = s;
#pragma unroll
    for (int off = 1; off < 16; off <<= 1) m = fmaxf(m, __shfl_xor(m, off));
    float e = __expf(s - m);
    float t = e;
#pragma unroll
    for (int off = 1; off < 16; off <<= 1) t += __shfl_xor(t, off);
    w4[j] = e / t;
  }
#pragma unroll
  for (int j = 0; j < 4; ++j) w_lds[wave][grp * 4 + j][g16] = w4[j];

  __syncthreads();

  // PV: lane -> h = g16, d = grp*32 .. +32
  float acc[32];
#pragma unroll
  for (int i = 0; i < 32; ++i) acc[i] = 0.f;
#pragma unroll
  for (int g = 0; g < 16; ++g) {
    const float wg = w_lds[wave][g16][g];
#pragma unroll
    for (int c = 0; c < 4; ++c) {
      bf16x8 xv = *reinterpret_cast<const bf16x8*>(&xs_lds[wave][g][grp * 32 + c * 8]);
#pragma unroll
      for (int j = 0; j < 8; ++j) acc[c * 8 + j] += wg * (float)xv[j];
    }
  }

  unsigned short* op = att + (size_t)token * E + g16 * DH + grp * 32;
#pragma unroll
  for (int c = 0; c < 4; ++c) {
    u16x8 o;
#pragma unroll
    for (int j = 0; j < 8; ++j) o[j] = f2bf(acc[c * 8 + j]);
    *reinterpret_cast<u16x8*>(op + c * 8) = o;
  }
}

// ---------------- launch ----------------
extern "C" void kernel_launch(void* const* d_in, const int* in_sizes, int n_in,
                              void* d_out, int out_size, void* d_ws, size_t ws_size,
                              hipStream_t stream) {
  const float* x     = (const float*)d_in[0];
  const float* Wz    = (const float*)d_in[1];
  const float* bz    = (const float*)d_in[2];
  const float* Wx    = (const float*)d_in[3];
  const float* bx    = (const float*)d_in[4];
  const float* phase = (const float*)d_in[5];
  const float* Wo    = (const float*)d_in[6];
  const float* bo    = (const float*)d_in[7];

  char* p = (char*)d_ws;
  unsigned short* x_bf   = (unsigned short*)p; p += (size_t)TOK * E * 2;
  unsigned short* mod_bf = (unsigned short*)p; p += (size_t)TOK * E * 2;
  unsigned short* xs_bf  = (unsigned short*)p; p += (size_t)TOK * E * 2;
  unsigned short* wz_bf  = (unsigned short*)p; p += (size_t)E * E * 2;
  unsigned short* wx_bf  = (unsigned short*)p; p += (size_t)E * E * 2;
  unsigned short* wo_bf  = (unsigned short*)p; p += (size_t)E * E * 2;
  float* bz_s            = (float*)p;          p += (size_t)E * 4;
  unsigned short* att_bf = mod_bf;  // in-place: each wave reads its token before writing

  cvt_plain<<<2048, 256, 0, stream>>>(x, x_bf, TOK * E / 8);
  cvt_plain<<<1024, 256, 0, stream>>>(Wx, wx_bf, E * E / 8);
  cvt_plain<<<1024, 256, 0, stream>>>(Wo, wo_bf, E * E / 8);
  cvt_scaled<<<1024, 256, 0, stream>>>(Wz, phase, wz_bf, E * E / 8);
  scale_bias<<<E / 256, 256, 0, stream>>>(bz, phase, bz_s);

  const dim3 ggrid((TOK / 128) * (E / 128));
  gemm_bt<true><<<ggrid, 256, 0, stream>>>(x_bf, wz_bf, bz_s, mod_bf, TOK, E, E);
  gemm_bt<true><<<ggrid, 256, 0, stream>>>(x_bf, wx_bf, bx, xs_bf, TOK, E, E);
  attn_kernel<<<TOK / 4, 256, 0, stream>>>(mod_bf, xs_bf, att_bf);
  gemm_bt<false><<<ggrid, 256, 0, stream>>>(att_bf, wo_bf, bo, (float*)d_out, TOK, E, E);
}

// Round 2
// 464.241 us; speedup vs baseline: 1.4347x; 1.4347x over previous
//
#include <hip/hip_runtime.h>
#include <hip/hip_bf16.h>

#define TOK 16384   // B*S
#define E 2048
#define DH 128

using bf16x8 = __attribute__((ext_vector_type(8))) __bf16;
using f32x4  = __attribute__((ext_vector_type(4))) float;
using u16x8  = __attribute__((ext_vector_type(8))) unsigned short;

static __device__ __forceinline__ unsigned short f2bf(float f) {
  union { float f; unsigned u; } x; x.f = f;
  unsigned r = x.u + 0x7fffu + ((x.u >> 16) & 1u);   // RNE
  return (unsigned short)(r >> 16);
}

static __device__ __forceinline__ void gload_lds16(const unsigned short* g, unsigned short* l) {
  __builtin_amdgcn_global_load_lds(
      (const __attribute__((address_space(1))) void*)g,
      (__attribute__((address_space(3))) void*)l, 16, 0, 0);
}

// ---------------- prep kernels ----------------
__global__ __launch_bounds__(256) void cvt_plain(const float* __restrict__ in,
                                                 unsigned short* __restrict__ out, int n8) {
  int stride = gridDim.x * blockDim.x;
  for (int i = blockIdx.x * blockDim.x + threadIdx.x; i < n8; i += stride) {
    const float4* p = reinterpret_cast<const float4*>(in) + (size_t)i * 2;
    float4 v0 = p[0], v1 = p[1];
    u16x8 o;
    o[0] = f2bf(v0.x); o[1] = f2bf(v0.y); o[2] = f2bf(v0.z); o[3] = f2bf(v0.w);
    o[4] = f2bf(v1.x); o[5] = f2bf(v1.y); o[6] = f2bf(v1.z); o[7] = f2bf(v1.w);
    *(reinterpret_cast<u16x8*>(out) + i) = o;
  }
}

__global__ __launch_bounds__(256) void cvt_scaled(const float* __restrict__ in,
                                                  const float* __restrict__ phase,
                                                  unsigned short* __restrict__ out, int n8) {
  const float rs = 0.08838834764831845f;  // 1/sqrt(128)
  int stride = gridDim.x * blockDim.x;
  for (int i = blockIdx.x * blockDim.x + threadIdx.x; i < n8; i += stride) {
    int row = i >> 8;
    float sc = sinf(phase[row]) * rs;
    const float4* p = reinterpret_cast<const float4*>(in) + (size_t)i * 2;
    float4 v0 = p[0], v1 = p[1];
    u16x8 o;
    o[0] = f2bf(v0.x * sc); o[1] = f2bf(v0.y * sc); o[2] = f2bf(v0.z * sc); o[3] = f2bf(v0.w * sc);
    o[4] = f2bf(v1.x * sc); o[5] = f2bf(v1.y * sc); o[6] = f2bf(v1.z * sc); o[7] = f2bf(v1.w * sc);
    *(reinterpret_cast<u16x8*>(out) + i) = o;
  }
}

__global__ __launch_bounds__(256) void scale_bias(const float* __restrict__ bz,
                                                  const float* __restrict__ phase,
                                                  float* __restrict__ out) {
  const float rs = 0.08838834764831845f;
  int i = blockIdx.x * blockDim.x + threadIdx.x;
  if (i < E) out[i] = bz[i] * sinf(phase[i]) * rs;
}

// ---------------- 256x256 8-phase GEMM (T1+T2+T3+T4+T5) ----------------
// C[M,N] = A[M,K] @ Bm[N,K]^T + bias.  512 thr = 8 waves (2M x 4N), BK=64,
// LDS 128 KiB = 2 dbuf x (A 256x64 + B 256x64) bf16, st-swizzled 16B slots.
#define MFMA16 __builtin_amdgcn_mfma_f32_16x16x32_bf16

// swizzled LDS fragment read: slot ^= row&7  (slot = 16B unit, 8 per 128B row)
static __device__ __forceinline__ bf16x8 ldf(const unsigned short* buf, int row, int slot) {
  return *reinterpret_cast<const bf16x8*>(buf + row * 64 + ((slot ^ (row & 7)) << 3));
}

// stage one 128-row half-tile: 2 x global_load_lds(16B) per thread.
// LDS dest linear; global source pre-swizzled (rule #21).
static __device__ __forceinline__ void stage_half(const unsigned short* gbase, int K_,
                                                  unsigned short* dsthalf,
                                                  int r, int slot, int wave) {
#pragma unroll
  for (int c = 0; c < 2; ++c)
    gload_lds16(gbase + (size_t)(c * 64 + r) * K_ + slot * 8,
                dsthalf + c * 4096 + wave * 512);
}

static __device__ __forceinline__ void quad(f32x4 (&acc)[8][4], const bf16x8 (&a)[4][2],
                                            const bf16x8 (&b)[2][2], int mh, int nh) {
#pragma unroll
  for (int mi = 0; mi < 4; ++mi)
#pragma unroll
    for (int ni = 0; ni < 2; ++ni)
#pragma unroll
      for (int kk = 0; kk < 2; ++kk)
        acc[mh * 4 + mi][nh * 2 + ni] =
            MFMA16(a[mi][kk], b[ni][kk], acc[mh * 4 + mi][nh * 2 + ni], 0, 0, 0);
}

#define PH_BAR()  __builtin_amdgcn_s_barrier()
#define PH_LGKM() do { asm volatile("s_waitcnt lgkmcnt(0)" ::: "memory"); \
                       __builtin_amdgcn_sched_barrier(0); } while (0)

template <bool LAST>
static __device__ __forceinline__ void k_iter(
    const unsigned short* __restrict__ Ag, const unsigned short* __restrict__ Bg,
    int K_, int t,
    unsigned short* sA0, unsigned short* sA1, unsigned short* sB0, unsigned short* sB1,
    int r, int slot, int wave, int grp, int rA, int rB, f32x4 (&acc)[8][4]) {
  const size_t k1 = (size_t)(t + 1) * 64, k2 = (size_t)(t + 2) * 64, k3 = (size_t)(t + 3) * 64;
  const size_t hB = (size_t)128 * K_;
  bf16x8 aF[4][2], b0F[2][2], b1F[2][2];

  // ---- ph1: tile t (buf0): read A.mh0 + B.nh0 ; stage t+1.A0 -> sA1.h0
#pragma unroll
  for (int mi = 0; mi < 4; ++mi)
#pragma unroll
    for (int kk = 0; kk < 2; ++kk) aF[mi][kk] = ldf(sA0, rA + mi * 16, kk * 4 + grp);
#pragma unroll
  for (int ni = 0; ni < 2; ++ni)
#pragma unroll
    for (int kk = 0; kk < 2; ++kk) b0F[ni][kk] = ldf(sB0, rB + ni * 16, kk * 4 + grp);
  stage_half(Ag + k1, K_, sA1, r, slot, wave);
  PH_BAR(); PH_LGKM();
  __builtin_amdgcn_s_setprio(1); quad(acc, aF, b0F, 0, 0); __builtin_amdgcn_s_setprio(0);
  PH_BAR();

  // ---- ph2: read B.nh1 ; stage t+1.A1 -> sA1.h1
#pragma unroll
  for (int ni = 0; ni < 2; ++ni)
#pragma unroll
    for (int kk = 0; kk < 2; ++kk) b1F[ni][kk] = ldf(sB0, rB + 32 + ni * 16, kk * 4 + grp);
  stage_half(Ag + hB + k1, K_, sA1 + 8192, r, slot, wave);
  PH_BAR(); PH_LGKM();
  __builtin_amdgcn_s_setprio(1); quad(acc, aF, b1F, 0, 1); __builtin_amdgcn_s_setprio(0);
  PH_BAR();

  // ---- ph3: read A.mh1 ; stage t+2.B0 -> sB0.h0
#pragma unroll
  for (int mi = 0; mi < 4; ++mi)
#pragma unroll
    for (int kk = 0; kk < 2; ++kk) aF[mi][kk] = ldf(sA0, rA + 64 + mi * 16, kk * 4 + grp);
  if (!LAST) stage_half(Bg + k2, K_, sB0, r, slot, wave);
  PH_BAR(); PH_LGKM();
  __builtin_amdgcn_s_setprio(1); quad(acc, aF, b1F, 1, 1); __builtin_amdgcn_s_setprio(0);
  PH_BAR();

  // ---- ph4: regs only ; stage t+2.B1 -> sB0.h1 ; counted vmcnt (tile t+1 landed)
  if (!LAST) {
    stage_half(Bg + hB + k2, K_, sB0 + 8192, r, slot, wave);
    asm volatile("s_waitcnt vmcnt(4)" ::: "memory");
  } else {
    asm volatile("s_waitcnt vmcnt(0)" ::: "memory");
  }
  PH_BAR();
  __builtin_amdgcn_s_setprio(1); quad(acc, aF, b0F, 1, 0); __builtin_amdgcn_s_setprio(0);
  PH_BAR();

  // ---- ph5: tile t+1 (buf1): read A.mh0 + B.nh0 ; stage t+2.A0 -> sA0.h0
#pragma unroll
  for (int mi = 0; mi < 4; ++mi)
#pragma unroll
    for (int kk = 0; kk < 2; ++kk) aF[mi][kk] = ldf(sA1, rA + mi * 16, kk * 4 + grp);
#pragma unroll
  for (int ni = 0; ni < 2; ++ni)
#pragma unroll
    for (int kk = 0; kk < 2; ++kk) b0F[ni][kk] = ldf(sB1, rB + ni * 16, kk * 4 + grp);
  if (!LAST) stage_half(Ag + k2, K_, sA0, r, slot, wave);
  PH_BAR(); PH_LGKM();
  __builtin_amdgcn_s_setprio(1); quad(acc, aF, b0F, 0, 0); __builtin_amdgcn_s_setprio(0);
  PH_BAR();

  // ---- ph6: read B.nh1 ; stage t+2.A1 -> sA0.h1
#pragma unroll
  for (int ni = 0; ni < 2; ++ni)
#pragma unroll
    for (int kk = 0; kk < 2; ++kk) b1F[ni][kk] = ldf(sB1, rB + 32 + ni * 16, kk * 4 + grp);
  if (!LAST) stage_half(Ag + hB + k2, K_, sA0 + 8192, r, slot, wave);
  PH_BAR(); PH_LGKM();
  __builtin_amdgcn_s_setprio(1); quad(acc, aF, b1F, 0, 1); __builtin_amdgcn_s_setprio(0);
  PH_BAR();

  // ---- ph7: read A.mh1 ; stage t+3.B0 -> sB1.h0
#pragma unroll
  for (int mi = 0; mi < 4; ++mi)
#pragma unroll
    for (int kk = 0; kk < 2; ++kk) aF[mi][kk] = ldf(sA1, rA + 64 + mi * 16, kk * 4 + grp);
  if (!LAST) stage_half(Bg + k3, K_, sB1, r, slot, wave);
  PH_BAR(); PH_LGKM();
  __builtin_amdgcn_s_setprio(1); quad(acc, aF, b1F, 1, 1); __builtin_amdgcn_s_setprio(0);
  PH_BAR();

  // ---- ph8: regs only ; stage t+3.B1 -> sB1.h1 ; counted vmcnt (tile t+2 landed)
  if (!LAST) {
    stage_half(Bg + hB + k3, K_, sB1 + 8192, r, slot, wave);
    asm volatile("s_waitcnt vmcnt(4)" ::: "memory");
  }
  PH_BAR();
  __builtin_amdgcn_s_setprio(1); quad(acc, aF, b0F, 1, 0); __builtin_amdgcn_s_setprio(0);
  PH_BAR();
}

template <bool OUT_BF16>
__global__ __launch_bounds__(512, 2) void gemm256(const unsigned short* __restrict__ A,
                                                  const unsigned short* __restrict__ Bm,
                                                  const float* __restrict__ bias,
                                                  void* __restrict__ C,
                                                  int M, int N, int K_) {
  extern __shared__ unsigned short lds[];
  unsigned short* sA0 = lds;
  unsigned short* sA1 = lds + 16384;
  unsigned short* sB0 = lds + 32768;
  unsigned short* sB1 = lds + 49152;

  const int nbn = N >> 8;
  const int bid = blockIdx.x;
  const int swz = (bid & 7) * ((int)gridDim.x >> 3) + (bid >> 3);  // XCD swizzle (nwg%8==0)
  const int by = swz / nbn, bx = swz % nbn;
  const int tm = by << 8, tn = bx << 8;

  const int tid = threadIdx.x;
  const int wave = tid >> 6, lane = tid & 63;
  const int g16 = lane & 15, grp = lane >> 4;
  const int wm = wave >> 2, wn = wave & 3;
  const int rA = wm * 128 + g16;
  const int rB = wn * 64 + g16;
  const int r = tid >> 3;
  const int slot = (tid & 7) ^ ((tid >> 3) & 7);

  const unsigned short* Ag = A + (size_t)tm * K_;
  const unsigned short* Bg = Bm + (size_t)tn * K_;
  const size_t hB = (size_t)128 * K_;

  f32x4 acc[8][4];
#pragma unroll
  for (int i = 0; i < 8; ++i)
#pragma unroll
    for (int j = 0; j < 4; ++j) acc[i][j] = (f32x4){0.f, 0.f, 0.f, 0.f};

  // prologue: t0 full (A0,A1,B0,B1) + t1.B0,B1  (12 loads/thread)
  stage_half(Ag, K_, sA0, r, slot, wave);
  stage_half(Ag + hB, K_, sA0 + 8192, r, slot, wave);
  stage_half(Bg, K_, sB0, r, slot, wave);
  stage_half(Bg + hB, K_, sB0 + 8192, r, slot, wave);
  stage_half(Bg + 64, K_, sB1, r, slot, wave);
  stage_half(Bg + hB + 64, K_, sB1 + 8192, r, slot, wave);
  asm volatile("s_waitcnt vmcnt(4)" ::: "memory");
  __builtin_amdgcn_s_barrier();

  const int NI = K_ >> 7;  // 2 K-tiles per iteration
#pragma unroll 1
  for (int i = 0; i < NI - 1; ++i)
    k_iter<false>(Ag, Bg, K_, 2 * i, sA0, sA1, sB0, sB1, r, slot, wave, grp, rA, rB, acc);
  k_iter<true>(Ag, Bg, K_, 2 * (NI - 1), sA0, sA1, sB0, sB1, r, slot, wave, grp, rA, rB, acc);

  // epilogue
#pragma unroll
  for (int mi = 0; mi < 8; ++mi) {
#pragma unroll
    for (int ni = 0; ni < 4; ++ni) {
      const int row = tm + wm * 128 + mi * 16 + grp * 4;
      const int col = tn + wn * 64 + ni * 16 + g16;
      const float bv = bias[col];
#pragma unroll
      for (int j = 0; j < 4; ++j) {
        const float v = acc[mi][ni][j] + bv;
        if (OUT_BF16)
          ((unsigned short*)C)[(size_t)(row + j) * N + col] = f2bf(v);
        else
          ((float*)C)[(size_t)(row + j) * N + col] = v;
      }
    }
  }
}

// ---------------- per-token head-mixing attention (unchanged, passed R1) ----------------
__global__ __launch_bounds__(256) void attn_kernel(const unsigned short* mod,
                                                   const unsigned short* xsg,
                                                   unsigned short* att) {
  __shared__ __align__(16) unsigned short xs_lds[4][16][136];
  __shared__ float w_lds[4][16][17];

  const int wave = threadIdx.x >> 6, lane = threadIdx.x & 63;
  const int token = (blockIdx.x << 2) | wave;
  const unsigned short* modp = mod + (size_t)token * E;
  const unsigned short* xsp  = xsg + (size_t)token * E;
  const int g16 = lane & 15, grp = lane >> 4;

  bf16x8 a[4], b[4];
#pragma unroll
  for (int kk = 0; kk < 4; ++kk) {
    a[kk] = *reinterpret_cast<const bf16x8*>(modp + g16 * DH + kk * 32 + grp * 8);
    b[kk] = *reinterpret_cast<const bf16x8*>(xsp  + g16 * DH + kk * 32 + grp * 8);
  }
#pragma unroll
  for (int kk = 0; kk < 4; ++kk)
    *reinterpret_cast<bf16x8*>(&xs_lds[wave][g16][kk * 32 + grp * 8]) = b[kk];

  f32x4 sc = (f32x4){0.f, 0.f, 0.f, 0.f};
#pragma unroll
  for (int kk = 0; kk < 4; ++kk)
    sc = MFMA16(a[kk], b[kk], sc, 0, 0, 0);

  float w4[4];
#pragma unroll
  for (int j = 0; j < 4; ++j) {
    float s = sc[j];
    float m = s;
#pragma unroll
    for (int off = 1; off < 16; off <<= 1) m = fmaxf(m, __shfl_xor(m, off));
    float e = __expf(s - m);
    float t = e;
#pragma unroll
    for (int off = 1; off < 16; off <<= 1) t += __shfl_xor(t, off);
    w4[j] = e / t;
  }
#pragma unroll
  for (int j = 0; j < 4; ++j) w_lds[wave][grp * 4 + j][g16] = w4[j];

  __syncthreads();

  float acc[32];
#pragma unroll
  for (int i = 0; i < 32; ++i) acc[i] = 0.f;
#pragma unroll
  for (int g = 0; g < 16; ++g) {
    const float wg = w_lds[wave][g16][g];
#pragma unroll
    for (int c = 0; c < 4; ++c) {
      bf16x8 xv = *reinterpret_cast<const bf16x8*>(&xs_lds[wave][g][grp * 32 + c * 8]);
#pragma unroll
      for (int j = 0; j < 8; ++j) acc[c * 8 + j] += wg * (float)xv[j];
    }
  }

  unsigned short* op = att + (size_t)token * E + g16 * DH + grp * 32;
#pragma unroll
  for (int c = 0; c < 4; ++c) {
    u16x8 o;
#pragma unroll
    for (int j = 0; j < 8; ++j) o[j] = f2bf(acc[c * 8 + j]);
    *reinterpret_cast<u16x8*>(op + c * 8) = o;
  }
}

// ---------------- launch ----------------
extern "C" void kernel_launch(void* const* d_in, const int* in_sizes, int n_in,
                              void* d_out, int out_size, void* d_ws, size_t ws_size,
                              hipStream_t stream) {
  const float* x     = (const float*)d_in[0];
  const float* Wz    = (const float*)d_in[1];
  const float* bz    = (const float*)d_in[2];
  const float* Wx    = (const float*)d_in[3];
  const float* bx    = (const float*)d_in[4];
  const float* phase = (const float*)d_in[5];
  const float* Wo    = (const float*)d_in[6];
  const float* bo    = (const float*)d_in[7];

  char* p = (char*)d_ws;
  unsigned short* x_bf   = (unsigned short*)p; p += (size_t)TOK * E * 2;
  unsigned short* mod_bf = (unsigned short*)p; p += (size_t)TOK * E * 2;
  unsigned short* xs_bf  = (unsigned short*)p; p += (size_t)TOK * E * 2;
  unsigned short* wz_bf  = (unsigned short*)p; p += (size_t)E * E * 2;
  unsigned short* wx_bf  = (unsigned short*)p; p += (size_t)E * E * 2;
  unsigned short* wo_bf  = (unsigned short*)p; p += (size_t)E * E * 2;
  float* bz_s            = (float*)p;          p += (size_t)E * 4;
  unsigned short* att_bf = mod_bf;  // in-place per-token rewrite

  hipFuncSetAttribute((const void*)gemm256<true>,
                      hipFuncAttributeMaxDynamicSharedMemorySize, 131072);
  hipFuncSetAttribute((const void*)gemm256<false>,
                      hipFuncAttributeMaxDynamicSharedMemorySize, 131072);

  cvt_plain<<<2048, 256, 0, stream>>>(x, x_bf, TOK * E / 8);
  cvt_plain<<<1024, 256, 0, stream>>>(Wx, wx_bf, E * E / 8);
  cvt_plain<<<1024, 256, 0, stream>>>(Wo, wo_bf, E * E / 8);
  cvt_scaled<<<1024, 256, 0, stream>>>(Wz, phase, wz_bf, E * E / 8);
  scale_bias<<<E / 256, 256, 0, stream>>>(bz, phase, bz_s);

  const dim3 ggrid((TOK / 256) * (E / 256));  // 512 wgs
  gemm256<true><<<ggrid, 512, 131072, stream>>>(x_bf, wz_bf, bz_s, mod_bf, TOK, E, E);
  gemm256<true><<<ggrid, 512, 131072, stream>>>(x_bf, wx_bf, bx, xs_bf, TOK, E, E);
  attn_kernel<<<TOK / 4, 256, 0, stream>>>(mod_bf, xs_bf, att_bf);
  gemm256<false><<<ggrid, 512, 131072, stream>>>(att_bf, wo_bf, bo, (float*)d_out, TOK, E, E);
}

// Round 3
// 455.807 us; speedup vs baseline: 1.4612x; 1.0185x over previous
//
#include <hip/hip_runtime.h>
#include <hip/hip_bf16.h>

#define TOK 16384   // B*S
#define E 2048
#define DH 128

using bf16x8 = __attribute__((ext_vector_type(8))) __bf16;
using f32x4  = __attribute__((ext_vector_type(4))) float;
using u16x8  = __attribute__((ext_vector_type(8))) unsigned short;

static __device__ __forceinline__ unsigned short f2bf(float f) {
  union { float f; unsigned u; } x; x.f = f;
  unsigned r = x.u + 0x7fffu + ((x.u >> 16) & 1u);   // RNE
  return (unsigned short)(r >> 16);
}

static __device__ __forceinline__ void gload_lds16(const unsigned short* g, unsigned short* l) {
  __builtin_amdgcn_global_load_lds(
      (const __attribute__((address_space(1))) void*)g,
      (__attribute__((address_space(3))) void*)l, 16, 0, 0);
}

// ---------------- prep kernels ----------------
__global__ __launch_bounds__(256) void cvt_plain(const float* __restrict__ in,
                                                 unsigned short* __restrict__ out, int n8) {
  int stride = gridDim.x * blockDim.x;
  for (int i = blockIdx.x * blockDim.x + threadIdx.x; i < n8; i += stride) {
    const float4* p = reinterpret_cast<const float4*>(in) + (size_t)i * 2;
    float4 v0 = p[0], v1 = p[1];
    u16x8 o;
    o[0] = f2bf(v0.x); o[1] = f2bf(v0.y); o[2] = f2bf(v0.z); o[3] = f2bf(v0.w);
    o[4] = f2bf(v1.x); o[5] = f2bf(v1.y); o[6] = f2bf(v1.z); o[7] = f2bf(v1.w);
    *(reinterpret_cast<u16x8*>(out) + i) = o;
  }
}

__global__ __launch_bounds__(256) void cvt_scaled(const float* __restrict__ in,
                                                  const float* __restrict__ phase,
                                                  unsigned short* __restrict__ out, int n8) {
  const float rs = 0.08838834764831845f;  // 1/sqrt(128)
  int stride = gridDim.x * blockDim.x;
  for (int i = blockIdx.x * blockDim.x + threadIdx.x; i < n8; i += stride) {
    int row = i >> 8;
    float sc = sinf(phase[row]) * rs;
    const float4* p = reinterpret_cast<const float4*>(in) + (size_t)i * 2;
    float4 v0 = p[0], v1 = p[1];
    u16x8 o;
    o[0] = f2bf(v0.x * sc); o[1] = f2bf(v0.y * sc); o[2] = f2bf(v0.z * sc); o[3] = f2bf(v0.w * sc);
    o[4] = f2bf(v1.x * sc); o[5] = f2bf(v1.y * sc); o[6] = f2bf(v1.z * sc); o[7] = f2bf(v1.w * sc);
    *(reinterpret_cast<u16x8*>(out) + i) = o;
  }
}

__global__ __launch_bounds__(256) void scale_bias(const float* __restrict__ bz,
                                                  const float* __restrict__ phase,
                                                  float* __restrict__ out) {
  const float rs = 0.08838834764831845f;
  int i = blockIdx.x * blockDim.x + threadIdx.x;
  if (i < E) out[i] = bz[i] * sinf(phase[i]) * rs;
}

// ---------------- 256x256 8-phase GEMM ----------------
#define MFMA16 __builtin_amdgcn_mfma_f32_16x16x32_bf16

// swizzled LDS fragment read: slot ^= row&7  (slot = 16B unit, 8 per 128B row)
static __device__ __forceinline__ bf16x8 ldf(const unsigned short* buf, int row, int slot) {
  return *reinterpret_cast<const bf16x8*>(buf + row * 64 + ((slot ^ (row & 7)) << 3));
}

// stage one 128-row half-tile: 2 x global_load_lds(16B) per thread.
static __device__ __forceinline__ void stage_half(const unsigned short* gbase, int K_,
                                                  unsigned short* dsthalf,
                                                  int r, int slot, int wave) {
#pragma unroll
  for (int c = 0; c < 2; ++c)
    gload_lds16(gbase + (size_t)(c * 64 + r) * K_ + slot * 8,
                dsthalf + c * 4096 + wave * 512);
}

static __device__ __forceinline__ void quad(f32x4 (&acc)[8][4], const bf16x8 (&a)[4][2],
                                            const bf16x8 (&b)[2][2], int mh, int nh) {
#pragma unroll
  for (int mi = 0; mi < 4; ++mi)
#pragma unroll
    for (int ni = 0; ni < 2; ++ni)
#pragma unroll
      for (int kk = 0; kk < 2; ++kk)
        acc[mh * 4 + mi][nh * 2 + ni] =
            MFMA16(a[mi][kk], b[ni][kk], acc[mh * 4 + mi][nh * 2 + ni], 0, 0, 0);
}

#define PH_BAR()  __builtin_amdgcn_s_barrier()
#define PH_LGKM() asm volatile("s_waitcnt lgkmcnt(0)" ::: "memory")
#define PRIO1()   __builtin_amdgcn_s_setprio(1)
#define PRIO0()   __builtin_amdgcn_s_setprio(0)

#define LD_A(dst, buf, base)                                             \
  _Pragma("unroll")                                                      \
  for (int mi = 0; mi < 4; ++mi)                                         \
    _Pragma("unroll")                                                    \
    for (int kk = 0; kk < 2; ++kk)                                       \
      dst[mi][kk] = ldf(buf, (base) + mi * 16, kk * 4 + grp);

#define LD_B(dst, buf, base)                                             \
  _Pragma("unroll")                                                      \
  for (int ni = 0; ni < 2; ++ni)                                         \
    _Pragma("unroll")                                                    \
    for (int kk = 0; kk < 2; ++kk)                                       \
      dst[ni][kk] = ldf(buf, (base) + ni * 16, kk * 4 + grp);

template <bool LAST>
static __device__ __forceinline__ void k_iter(
    const unsigned short* __restrict__ Ag, const unsigned short* __restrict__ Bg,
    int K_, int t,
    unsigned short* sA0, unsigned short* sA1, unsigned short* sB0, unsigned short* sB1,
    int r, int slot, int wave, int grp, int rA, int rB,
    bf16x8 (&bP)[2][2], bf16x8 (&bQ)[2][2], f32x4 (&acc)[8][4]) {
  const size_t k1 = (size_t)(t + 1) * 64, k2 = (size_t)(t + 2) * 64, k3 = (size_t)(t + 3) * 64;
  const size_t hB = (size_t)128 * K_;
  bf16x8 aF[4][2], b1F[2][2];

  // ---- ph1: read A.mh0 (8) ; stage t+1.A0
  LD_A(aF, sA0, rA);
  stage_half(Ag + k1, K_, sA1, r, slot, wave);
  PH_BAR(); PH_LGKM();
  PRIO1(); quad(acc, aF, bP, 0, 0); PRIO0();
  PH_BAR();

  // ---- ph2: read B.nh1 (4) ; stage t+1.A1
  LD_B(b1F, sB0, rB + 32);
  stage_half(Ag + hB + k1, K_, sA1 + 8192, r, slot, wave);
  PH_BAR(); PH_LGKM();
  PRIO1(); quad(acc, aF, b1F, 0, 1); PRIO0();
  PH_BAR();

  // ---- ph3: read A.mh1 (8) ; stage t+2.B0
  LD_A(aF, sA0, rA + 64);
  if (!LAST) stage_half(Bg + k2, K_, sB0, r, slot, wave);
  PH_BAR(); PH_LGKM();
  PRIO1(); quad(acc, aF, b1F, 1, 1); PRIO0();
  PH_BAR();

  // ---- ph4: stage t+2.B1 ; counted vmcnt (t+1 landed) ; MFMA ; prefetch bQ = B(t+1).nh0
  if (!LAST) {
    stage_half(Bg + hB + k2, K_, sB0 + 8192, r, slot, wave);
    asm volatile("s_waitcnt vmcnt(4)" ::: "memory");
  } else {
    asm volatile("s_waitcnt vmcnt(0)" ::: "memory");
  }
  PH_BAR();
  PRIO1(); quad(acc, aF, bP, 1, 0); PRIO0();
  LD_B(bQ, sB1, rB);
  PH_BAR();

  // ---- ph5: read A.mh0 (8) from buf1 ; stage t+2.A0
  LD_A(aF, sA1, rA);
  if (!LAST) stage_half(Ag + k2, K_, sA0, r, slot, wave);
  PH_BAR(); PH_LGKM();
  PRIO1(); quad(acc, aF, bQ, 0, 0); PRIO0();
  PH_BAR();

  // ---- ph6: read B.nh1 (4) ; stage t+2.A1
  LD_B(b1F, sB1, rB + 32);
  if (!LAST) stage_half(Ag + hB + k2, K_, sA0 + 8192, r, slot, wave);
  PH_BAR(); PH_LGKM();
  PRIO1(); quad(acc, aF, b1F, 0, 1); PRIO0();
  PH_BAR();

  // ---- ph7: read A.mh1 (8) ; stage t+3.B0
  LD_A(aF, sA1, rA + 64);
  if (!LAST) stage_half(Bg + k3, K_, sB1, r, slot, wave);
  PH_BAR(); PH_LGKM();
  PRIO1(); quad(acc, aF, b1F, 1, 1); PRIO0();
  PH_BAR();

  // ---- ph8: stage t+3.B1 ; counted vmcnt (t+2 landed) ; MFMA ; prefetch bP = B(t+2).nh0
  if (!LAST) {
    stage_half(Bg + hB + k3, K_, sB1 + 8192, r, slot, wave);
    asm volatile("s_waitcnt vmcnt(4)" ::: "memory");
  }
  PH_BAR();
  PRIO1(); quad(acc, aF, bQ, 1, 0); PRIO0();
  if (!LAST) { LD_B(bP, sB0, rB); }
  PH_BAR();
}

template <bool OUT_BF16>
__global__ __launch_bounds__(512, 2) void gemm256(const unsigned short* __restrict__ A,
                                                  const unsigned short* __restrict__ Bm,
                                                  const float* __restrict__ bias,
                                                  void* __restrict__ C,
                                                  int M, int N, int K_) {
  extern __shared__ unsigned short lds[];
  unsigned short* sA0 = lds;
  unsigned short* sA1 = lds + 16384;
  unsigned short* sB0 = lds + 32768;
  unsigned short* sB1 = lds + 49152;

  const int nbn = N >> 8;
  const int bid = blockIdx.x;
  const int swz = (bid & 7) * ((int)gridDim.x >> 3) + (bid >> 3);  // XCD swizzle (nwg%8==0)
  const int by = swz / nbn, bx = swz % nbn;
  const int tm = by << 8, tn = bx << 8;

  const int tid = threadIdx.x;
  const int wave = tid >> 6, lane = tid & 63;
  const int g16 = lane & 15, grp = lane >> 4;
  const int wm = wave >> 2, wn = wave & 3;
  const int rA = wm * 128 + g16;
  const int rB = wn * 64 + g16;
  const int r = tid >> 3;
  const int slot = (tid & 7) ^ ((tid >> 3) & 7);

  const unsigned short* Ag = A + (size_t)tm * K_;
  const unsigned short* Bg = Bm + (size_t)tn * K_;
  const size_t hB = (size_t)128 * K_;

  f32x4 acc[8][4];
#pragma unroll
  for (int i = 0; i < 8; ++i)
#pragma unroll
    for (int j = 0; j < 4; ++j) acc[i][j] = (f32x4){0.f, 0.f, 0.f, 0.f};

  bf16x8 bP[2][2], bQ[2][2];

  // prologue: t0 full (A0,A1,B0,B1) + t1.B0,B1  (12 loads/thread)
  stage_half(Ag, K_, sA0, r, slot, wave);
  stage_half(Ag + hB, K_, sA0 + 8192, r, slot, wave);
  stage_half(Bg, K_, sB0, r, slot, wave);
  stage_half(Bg + hB, K_, sB0 + 8192, r, slot, wave);
  stage_half(Bg + 64, K_, sB1, r, slot, wave);
  stage_half(Bg + hB + 64, K_, sB1 + 8192, r, slot, wave);
  asm volatile("s_waitcnt vmcnt(4)" ::: "memory");
  __builtin_amdgcn_s_barrier();
  LD_B(bP, sB0, rB);   // B(t0).nh0 ; drained by ph1's lgkmcnt(0)

  const int NI = E >> 7;  // 2 K-tiles per iteration
#pragma unroll 1
  for (int i = 0; i < NI - 1; ++i)
    k_iter<false>(Ag, Bg, K_, 2 * i, sA0, sA1, sB0, sB1, r, slot, wave, grp, rA, rB, bP, bQ, acc);
  k_iter<true>(Ag, Bg, K_, 2 * (NI - 1), sA0, sA1, sB0, sB1, r, slot, wave, grp, rA, rB, bP, bQ, acc);

  // epilogue
#pragma unroll
  for (int mi = 0; mi < 8; ++mi) {
#pragma unroll
    for (int ni = 0; ni < 4; ++ni) {
      const int row = tm + wm * 128 + mi * 16 + grp * 4;
      const int col = tn + wn * 64 + ni * 16 + g16;
      const float bv = bias[col];
#pragma unroll
      for (int j = 0; j < 4; ++j) {
        const float v = acc[mi][ni][j] + bv;
        if (OUT_BF16)
          ((unsigned short*)C)[(size_t)(row + j) * N + col] = f2bf(v);
        else
          ((float*)C)[(size_t)(row + j) * N + col] = v;
      }
    }
  }
}

// ---------------- per-token head-mixing attention ----------------
__global__ __launch_bounds__(256) void attn_kernel(const unsigned short* mod,
                                                   const unsigned short* xsg,
                                                   unsigned short* att) {
  __shared__ __align__(16) unsigned short xs_lds[4][16][136];
  __shared__ float w_lds[4][16][17];

  const int wave = threadIdx.x >> 6, lane = threadIdx.x & 63;
  const int token = (blockIdx.x << 2) | wave;
  const unsigned short* modp = mod + (size_t)token * E;
  const unsigned short* xsp  = xsg + (size_t)token * E;
  const int g16 = lane & 15, grp = lane >> 4;

  bf16x8 a[4], b[4];
#pragma unroll
  for (int kk = 0; kk < 4; ++kk) {
    a[kk] = *reinterpret_cast<const bf16x8*>(modp + g16 * DH + kk * 32 + grp * 8);
    b[kk] = *reinterpret_cast<const bf16x8*>(xsp  + g16 * DH + kk * 32 + grp * 8);
  }
#pragma unroll
  for (int kk = 0; kk < 4; ++kk)
    *reinterpret_cast<bf16x8*>(&xs_lds[wave][g16][kk * 32 + grp * 8]) = b[kk];

  f32x4 sc = (f32x4){0.f, 0.f, 0.f, 0.f};
#pragma unroll
  for (int kk = 0; kk < 4; ++kk)
    sc = MFMA16(a[kk], b[kk], sc, 0, 0, 0);

  float w4[4];
#pragma unroll
  for (int j = 0; j < 4; ++j) {
    float s = sc[j];
    float m = s;
#pragma unroll
    for (int off = 1; off < 16; off <<= 1) m = fmaxf(m, __shfl_xor(m, off));
    float e = __expf(s - m);
    float t = e;
#pragma unroll
    for (int off = 1; off < 16; off <<= 1) t += __shfl_xor(t, off);
    w4[j] = e / t;
  }
#pragma unroll
  for (int j = 0; j < 4; ++j) w_lds[wave][grp * 4 + j][g16] = w4[j];

  __syncthreads();

  float acc[32];
#pragma unroll
  for (int i = 0; i < 32; ++i) acc[i] = 0.f;
#pragma unroll
  for (int g = 0; g < 16; ++g) {
    const float wg = w_lds[wave][g16][g];
#pragma unroll
    for (int c = 0; c < 4; ++c) {
      bf16x8 xv = *reinterpret_cast<const bf16x8*>(&xs_lds[wave][g][grp * 32 + c * 8]);
#pragma unroll
      for (int j = 0; j < 8; ++j) acc[c * 8 + j] += wg * (float)xv[j];
    }
  }

  unsigned short* op = att + (size_t)token * E + g16 * DH + grp * 32;
#pragma unroll
  for (int c = 0; c < 4; ++c) {
    u16x8 o;
#pragma unroll
    for (int j = 0; j < 8; ++j) o[j] = f2bf(acc[c * 8 + j]);
    *reinterpret_cast<u16x8*>(op + c * 8) = o;
  }
}

// ---------------- launch ----------------
extern "C" void kernel_launch(void* const* d_in, const int* in_sizes, int n_in,
                              void* d_out, int out_size, void* d_ws, size_t ws_size,
                              hipStream_t stream) {
  const float* x     = (const float*)d_in[0];
  const float* Wz    = (const float*)d_in[1];
  const float* bz    = (const float*)d_in[2];
  const float* Wx    = (const float*)d_in[3];
  const float* bx    = (const float*)d_in[4];
  const float* phase = (const float*)d_in[5];
  const float* Wo    = (const float*)d_in[6];
  const float* bo    = (const float*)d_in[7];

  char* p = (char*)d_ws;
  unsigned short* x_bf   = (unsigned short*)p; p += (size_t)TOK * E * 2;
  unsigned short* mod_bf = (unsigned short*)p; p += (size_t)TOK * E * 2;
  unsigned short* xs_bf  = (unsigned short*)p; p += (size_t)TOK * E * 2;
  unsigned short* wz_bf  = (unsigned short*)p; p += (size_t)E * E * 2;
  unsigned short* wx_bf  = (unsigned short*)p; p += (size_t)E * E * 2;
  unsigned short* wo_bf  = (unsigned short*)p; p += (size_t)E * E * 2;
  float* bz_s            = (float*)p;          p += (size_t)E * 4;
  unsigned short* att_bf = mod_bf;  // in-place per-token rewrite

  hipFuncSetAttribute((const void*)gemm256<true>,
                      hipFuncAttributeMaxDynamicSharedMemorySize, 131072);
  hipFuncSetAttribute((const void*)gemm256<false>,
                      hipFuncAttributeMaxDynamicSharedMemorySize, 131072);

  cvt_plain<<<2048, 256, 0, stream>>>(x, x_bf, TOK * E / 8);
  cvt_plain<<<1024, 256, 0, stream>>>(Wx, wx_bf, E * E / 8);
  cvt_plain<<<1024, 256, 0, stream>>>(Wo, wo_bf, E * E / 8);
  cvt_scaled<<<1024, 256, 0, stream>>>(Wz, phase, wz_bf, E * E / 8);
  scale_bias<<<E / 256, 256, 0, stream>>>(bz, phase, bz_s);

  const dim3 ggrid((TOK / 256) * (E / 256));  // 512 wgs
  gemm256<true><<<ggrid, 512, 131072, stream>>>(x_bf, wz_bf, bz_s, mod_bf, TOK, E, E);
  gemm256<true><<<ggrid, 512, 131072, stream>>>(x_bf, wx_bf, bx, xs_bf, TOK, E, E);
  attn_kernel<<<TOK / 4, 256, 0, stream>>>(mod_bf, xs_bf, att_bf);
  gemm256<false><<<ggrid, 512, 131072, stream>>>(att_bf, wo_bf, bo, (float*)d_out, TOK, E, E);
}